// Round 6
// baseline (466.290 us; speedup 1.0000x reference)
//
#include <hip/hip_runtime.h>
#include <hip/hip_bf16.h>

// B=2, C=512, H=W=64 -> N=4096, 32 groups of 16 channels
#define BATCH 2
#define CDIM 512
#define NDIM 4096
#define NGROUPS 32
#define CHPG 16
#define GN_EPS 1e-6f

typedef __attribute__((ext_vector_type(8))) short bf16x8;   // 8 bf16 = 4 VGPRs
typedef __attribute__((ext_vector_type(4))) float f32x4;

__device__ __forceinline__ void gl_lds16(const void* g, void* lds) {
  __builtin_amdgcn_global_load_lds((__attribute__((address_space(1))) void*)(g),
                                   (__attribute__((address_space(3))) void*)(lds), 16, 0, 0);
}

template <int N>
__device__ __forceinline__ void wait_vmcnt() {
  if constexpr (N == 1) asm volatile("s_waitcnt vmcnt(1)" ::: "memory");
  else if constexpr (N == 2) asm volatile("s_waitcnt vmcnt(2)" ::: "memory");
  else if constexpr (N == 3) asm volatile("s_waitcnt vmcnt(3)" ::: "memory");
  else if constexpr (N == 4) asm volatile("s_waitcnt vmcnt(4)" ::: "memory");
  else if constexpr (N == 5) asm volatile("s_waitcnt vmcnt(5)" ::: "memory");
  else if constexpr (N == 6) asm volatile("s_waitcnt vmcnt(6)" ::: "memory");
  else if constexpr (N == 8) asm volatile("s_waitcnt vmcnt(8)" ::: "memory");
  else if constexpr (N == 12) asm volatile("s_waitcnt vmcnt(12)" ::: "memory");
  else asm volatile("s_waitcnt vmcnt(8)" ::: "memory");
}

__device__ __forceinline__ void raw_barrier() {
  asm volatile("s_barrier" ::: "memory");
}

__device__ __forceinline__ void drain_vm() {
  asm volatile("s_waitcnt vmcnt(0)" ::: "memory");
}

__device__ __forceinline__ short bf16_bits(float v) {
  __hip_bfloat16 h = __float2bfloat16(v);
  union { __hip_bfloat16 h; short s; } u;
  u.h = h;
  return u.s;
}

// ---------------- GroupNorm stats, two-stage ----------------
__global__ __launch_bounds__(256) void gn_stats_p1(const float* __restrict__ x,
                                                   float2* __restrict__ part) {
  int blk = blockIdx.x;
  int chunk = blk & 15, bg = blk >> 4;
  const float4* p = (const float4*)(x + (size_t)bg * (CHPG * NDIM) + chunk * 4096);
  float s = 0.f, ss = 0.f;
#pragma unroll
  for (int t = 0; t < 4; t++) {
    float4 v = p[threadIdx.x + t * 256];
    s += v.x + v.y + v.z + v.w;
    ss += v.x * v.x + v.y * v.y + v.z * v.z + v.w * v.w;
  }
  int w = threadIdx.x >> 6, l = threadIdx.x & 63;
#pragma unroll
  for (int off = 32; off > 0; off >>= 1) {
    s += __shfl_down(s, off);
    ss += __shfl_down(ss, off);
  }
  __shared__ float r1[4], r2[4];
  if (l == 0) { r1[w] = s; r2[w] = ss; }
  __syncthreads();
  if (threadIdx.x == 0)
    part[blk] = make_float2(r1[0] + r1[1] + r1[2] + r1[3], r2[0] + r2[1] + r2[2] + r2[3]);
}

__global__ __launch_bounds__(64) void gn_stats_p2(const float2* __restrict__ part,
                                                  float2* __restrict__ stats) {
  int bg = threadIdx.x;  // 64
  float s = 0.f, ss = 0.f;
#pragma unroll
  for (int c = 0; c < 16; c++) {
    float2 v = part[bg * 16 + c];
    s += v.x; ss += v.y;
  }
  const float inv = 1.0f / (CHPG * NDIM);
  float mean = s * inv;
  float var = ss * inv - mean * mean;
  stats[bg] = make_float2(mean, rsqrtf(var + GN_EPS));
}

// ------ GroupNorm apply + transpose to channel-last bf16: h_t[b][n][c] ------
__global__ __launch_bounds__(256) void gn_apply_t(const float* __restrict__ x,
                                                  const float2* __restrict__ stats,
                                                  const float* __restrict__ w,
                                                  const float* __restrict__ bias,
                                                  __hip_bfloat16* __restrict__ ht) {
  __shared__ __hip_bfloat16 tile[64][66];
  int b = blockIdx.z, c0 = blockIdx.y * 64, n0 = blockIdx.x * 64;
  int tq = threadIdx.x >> 6;
  int tl = threadIdx.x & 63;
#pragma unroll
  for (int i = 0; i < 16; i++) {
    int cl = tq * 16 + i;
    int c = c0 + cl;
    float2 st = stats[b * NGROUPS + (c >> 4)];
    float v = x[((size_t)b * CDIM + c) * NDIM + n0 + tl];
    v = (v - st.x) * st.y * w[c] + bias[c];
    tile[tl][cl] = __float2bfloat16(v);
  }
  __syncthreads();
#pragma unroll
  for (int i = 0; i < 16; i++) {
    int nl = tq * 16 + i;
    ht[((size_t)b * NDIM + n0 + nl) * CDIM + c0 + tl] = tile[nl][tl];
  }
}

// --- fp32 -> bf16 weights; also concat [bq;bk] bias into bqk (block 0) ---
__global__ __launch_bounds__(256) void cvt_w(const float* __restrict__ a, const float* __restrict__ b,
                                             const float* __restrict__ c, const float* __restrict__ d,
                                             __hip_bfloat16* __restrict__ o,
                                             const float* __restrict__ bq, const float* __restrict__ bk,
                                             float* __restrict__ bqk) {
  int i = blockIdx.x * 256 + threadIdx.x;
  o[i]          = __float2bfloat16(a[i]);
  o[i + 262144] = __float2bfloat16(b[i]);
  o[i + 524288] = __float2bfloat16(c[i]);
  o[i + 786432] = __float2bfloat16(d[i]);
  if (blockIdx.x == 0) {
#pragma unroll
    for (int t = 0; t < 4; t++) {
      int j = threadIdx.x + t * 256;  // 0..1023
      bqk[j] = (j < 512) ? bq[j] : bk[j - 512];
    }
  }
}

// ---------------- MFMA NT GEMM, pipelined + LDS-swizzled ----------------
// (used for qk / v / out dispatches; S and PV replaced by fused_spv)
template <int MT, int NT, int KU, int BIAS_MODE, bool HAS_RES, int OUT_MODE,
          bool EXPZ, bool SCALEM, bool SWIZ, int MINB, int NBUF>
__global__ __launch_bounds__(256, MINB) void mfma_gemm_nt(
    const __hip_bfloat16* __restrict__ A, const __hip_bfloat16* __restrict__ B,
    const float* __restrict__ bias, const float* __restrict__ res,
    void* __restrict__ Cout, float* __restrict__ zsum_g, const float* __restrict__ cinv_g,
    int M, int N, int K, long sA, long sB, long sC,
    long lda, long ldb, long ldc, float scale) {
  constexpr int MTI = MT / 32, NTI = NT / 32;   // 16x16 acc tiles per wave
  constexpr int SB = 64 * KU;                   // bytes per row k-slab
  constexpr int ABYT = MT * SB, BBYT = NT * SB;
  constexpr int BUFB = ABYT + BBYT;
  constexpr int AISS = MT * KU / 64, BISS = NT * KU / 64;
  constexpr int NL = AISS + BISS;
  constexpr int RPI = 16 / KU;                  // rows per staging issue
  constexpr int ES = (OUT_MODE == 0) ? 4 : 2;   // out element size
  constexpr int RS = NT * ES + 16;              // repack row stride (pad = 16B)
  constexpr int REPB = MT * RS;
  constexpr int SMEMB = (NBUF * BUFB > REPB) ? NBUF * BUFB : REPB;
  constexpr int CPR = NT * ES / 16;             // 16B chunks per row
  constexpr int NCH = MT * CPR / 256;           // chunks per thread
  __shared__ char smem[SMEMB];
  const int tid = threadIdx.x;
  const int w = tid >> 6, l = tid & 63;
  const int wy = w >> 1, wx = w & 1;
  const int bz = blockIdx.z;
  int bx = blockIdx.x, by = blockIdx.y;
  if constexpr (SWIZ) {
    int l2 = by * gridDim.x + bx;
    int xcd = l2 & 7, s = l2 >> 3;
    by = xcd + (s & 3) * 8;
    bx = s >> 2;
  }
  const int m0 = by * MT, n0 = bx * NT;
  f32x4 acc[MTI][NTI] = {};

  // staging source column swizzle (bytes within the SB row-slab)
  int so;
  if constexpr (KU == 1) so = (((l & 3) - (l >> 2) - (l >> 4)) & 3) * 16;
  else                   so = (((l & 7) - (l >> 3)) & 7) * 16;
  const int lrow = (KU == 1) ? (l >> 2) : (l >> 3);
  const int arow = w * (MT / 4) + lrow;
  const int brow = w * (NT / 4) + lrow;
  const char* Ag = (const char*)A + ((size_t)bz * sA + (size_t)(m0 + arow) * lda) * 2 + so;
  const char* Bg = (const char*)B + ((size_t)bz * sB + (size_t)(n0 + brow) * ldb) * 2 + so;
  const size_t iadvA = (size_t)RPI * lda * 2;
  const size_t iadvB = (size_t)RPI * ldb * 2;
  const int woffA = w * (MT / 4) * SB;
  const int woffB = ABYT + w * (NT / 4) * SB;

  auto issue = [&](int buf) {
    char* base = smem + buf * BUFB;
#pragma unroll
    for (int i = 0; i < AISS; i++) gl_lds16(Ag + i * iadvA, base + woffA + i * 1024);
#pragma unroll
    for (int i = 0; i < BISS; i++) gl_lds16(Bg + i * iadvB, base + woffB + i * 1024);
    Ag += SB; Bg += SB;
  };

  // fragment-read column offsets (per KU half)
  const int x = l & 15;
  int qr0, qr1 = 0;
  if constexpr (KU == 1) {
    qr0 = (((l >> 4) + x + (x >> 2)) & 3) * 16;
  } else {
    qr0 = (((l >> 4) + (l & 7)) & 7) * 16;
    qr1 = (((l >> 4) + 4 + (l & 7)) & 7) * 16;
  }

  issue(0);
  if constexpr (NBUF == 3) issue(1);
  const int T = K / (32 * KU);
  for (int t = 0; t < T; t++) {
    issue((t + NBUF - 1) % NBUF);   // prefetch t+NBUF-1 (tail overshoots <=(NBUF-1)*SB, lands in ws)
    wait_vmcnt<(NBUF - 1) * NL>();  // oldest in-flight slab (t) landed
    raw_barrier();
    const char* Asb = smem + (t % NBUF) * BUFB;
    const char* Bsb = Asb + ABYT;
#pragma unroll
    for (int h = 0; h < KU; h++) {
      const int q = (h == 0) ? qr0 : qr1;
      bf16x8 af[MTI], bfr[NTI];
#pragma unroll
      for (int mt = 0; mt < MTI; mt++)
        af[mt] = *(const bf16x8*)(Asb + (wy * (MT / 2) + mt * 16 + x) * SB + q);
#pragma unroll
      for (int nt = 0; nt < NTI; nt++)
        bfr[nt] = *(const bf16x8*)(Bsb + (wx * (NT / 2) + nt * 16 + x) * SB + q);
#pragma unroll
      for (int mt = 0; mt < MTI; mt++)
#pragma unroll
        for (int nt = 0; nt < NTI; nt++)
          acc[mt][nt] = __builtin_amdgcn_mfma_f32_16x16x32_bf16(af[mt], bfr[nt], acc[mt][nt], 0, 0, 0);
    }
    raw_barrier();            // all waves done reading buf before it is overwritten
  }

  // ---- epilogue: value phase -> LDS repack -> coalesced store phase ----
  drain_vm();      // stray tail prefetches landed
  raw_barrier();
  const size_t cbase = (size_t)bz * sC;
#pragma unroll
  for (int mt = 0; mt < MTI; mt++) {
#pragma unroll
    for (int r = 0; r < 4; r++) {
      const int row = wy * (MT / 2) + mt * 16 + (l >> 4) * 4 + r;  // block-local m
      float bvm = (BIAS_MODE == 1) ? bias[m0 + row] : 0.f;
      float cm = 1.f;
      if constexpr (SCALEM) cm = cinv_g[(size_t)bz * M + m0 + row];
      float z = 0.f;
#pragma unroll
      for (int nt = 0; nt < NTI; nt++) {
        const int nl = wx * (NT / 2) + nt * 16 + x;
        float v = acc[mt][nt][r] * scale + bvm;
        if (BIAS_MODE == 2) v += bias[n0 + nl];
        if constexpr (EXPZ) { v = __builtin_amdgcn_exp2f(v); z += v; }
        if constexpr (SCALEM) v *= cm;
        if (OUT_MODE == 0) *(float*)(smem + row * RS + nl * 4) = v;
        else *(short*)(smem + row * RS + nl * 2) = bf16_bits(v);
      }
      if constexpr (EXPZ) {
        z += __shfl_xor(z, 1); z += __shfl_xor(z, 2);
        z += __shfl_xor(z, 4); z += __shfl_xor(z, 8);
        if (x == 0)
          zsum_g[((size_t)bz * 64 + bx * 2 + wx) * M + m0 + row] = z;
      }
    }
  }
  __syncthreads();
#pragma unroll
  for (int i = 0; i < NCH; i++) {
    const int g = i * 256 + tid;
    const int row = g / CPR;
    const int off = (g % CPR) * 16;
    char* dst = (char*)Cout + (cbase + (size_t)(m0 + row) * ldc + n0) * ES + off;
    if (OUT_MODE == 0) {
      float4 d = *(float4*)(smem + row * RS + off);
      if constexpr (HAS_RES) {
        float4 rv = *(const float4*)((const char*)res + (cbase + (size_t)(m0 + row) * ldc + n0) * 4 + off);
        d.x += rv.x; d.y += rv.y; d.z += rv.z; d.w += rv.w;
      }
      *(float4*)dst = d;
    } else {
      int4 d = *(int4*)(smem + row * RS + off);
      *(int4*)dst = d;
    }
  }
}

// ---------------- Fused S+PV: pvp[chunk][m][c] = sum_{n in chunk} exp2(s*k_m.q_n) * v[c][n] ----------------
// Per block: m-tile 64 x n-chunk 1024 (8 n-tiles of 128). E mini-GEMM (BK=64,
// dbuf staging, counted vmcnt) -> exp2 -> bf16 E-LDS tile (XOR-swizzled) ->
// PV contraction with vb read direct-from-global (B-frag layout = row-major n).
// acc2[64m x 512c] in regs (128 VGPR); z[m] in regs; 4 f32 partial outputs.
// grid 512 linear = (b2 x chunk4 x mtile64), XCD-grouped: one (b,chunk) pair
// per XCD -> its 1 MB q-chunk stays L2-resident. 2 blocks/CU.
__global__ __launch_bounds__(256, 2) void fused_spv(
    const __hip_bfloat16* __restrict__ qk_t,   // [B][4096][1024]; q at 0, k at +512
    const __hip_bfloat16* __restrict__ vbm,    // [B][512][4096]
    float* __restrict__ pvp,                   // [B][4][4096][512] f32
    float* __restrict__ zsum_g,                // [B][4][4096]
    float scale) {
  constexpr int KBUF = 8192;                   // k-slab [64][128B]
  constexpr int SLAB = KBUF + 16384;           // + q-slab [128][128B] = 24576
  __shared__ char smem[2 * SLAB + 16384 + 1024];
  char* const elds = smem + 2 * SLAB;          // E tile [64][256B], swizzled
  float* const zbuf = (float*)(smem + 2 * SLAB + 16384);  // [4][64]

  const int tid = threadIdx.x;
  const int l = tid & 63, w = tid >> 6;        // 4 waves; w = n-quarter (E) / c-quarter (PV)
  const int x = l & 15, hi = l >> 4;

  // block decode with XCD grouping: pair (b,chunk) <- lin&7, mtile <- lin>>3
  const int lin = blockIdx.x;
  const int pr = lin & 7;
  const int bz = pr >> 2, chunk = pr & 3, mt0 = lin >> 3;
  const int m0 = mt0 * 64;
  const int nc0 = chunk * 1024;

  const size_t qkbase = (size_t)bz * (4096L * 1024);
  const char* kg = (const char*)(qk_t + qkbase + 512);
  const char* qg = (const char*)(qk_t + qkbase);
  const char* vg = (const char*)(vbm + (size_t)bz * (512L * 4096));

  // staging swizzle: LDS[row][s] = G[row][(s + (row&7)) & 7]  (16B slots)
  const int so = (((tid & 7) + ((tid >> 3) & 7)) & 7) * 16;

  f32x4 acc2[4][8] = {};   // [mt][ct] -> rows mt*16+hi*4+r, cols w*128+ct*16+x
  float zr[4][4] = {};     // [mt][r]

  auto stage = [&](char* buf, int t, int kk) {
    const int kkb = kk * 128;
#pragma unroll
    for (int i = 0; i < 2; i++)
      gl_lds16(kg + (size_t)(m0 + i * 32 + (tid >> 3)) * 2048 + kkb + so,
               buf + i * 4096 + w * 1024);
#pragma unroll
    for (int i = 0; i < 4; i++)
      gl_lds16(qg + (size_t)(nc0 + t * 128 + i * 32 + (tid >> 3)) * 2048 + kkb + so,
               buf + KBUF + i * 4096 + w * 1024);
  };

  stage(smem, 0, 0);   // prologue: tile 0, kk 0 -> buf0

  for (int t = 0; t < 8; t++) {
    // ---- E mini-GEMM over K=512 ----
    f32x4 eacc[4][2] = {};
    for (int kk = 0; kk < 8; kk++) {
      if (kk < 7) {
        stage(smem + ((kk + 1) & 1) * SLAB, t, kk + 1);
        wait_vmcnt<6>();            // slab kk landed (kk+1 in flight)
      } else {
        drain_vm();
      }
      raw_barrier();
      const char* kb = smem + (kk & 1) * SLAB;
      const char* qb = kb + KBUF;
#pragma unroll
      for (int h = 0; h < 2; h++) {
        const int qo = ((h * 4 + hi - (l & 7)) & 7) * 16;
        bf16x8 af[4], bf[2];
#pragma unroll
        for (int mt = 0; mt < 4; mt++)
          af[mt] = *(const bf16x8*)(kb + (mt * 16 + x) * 128 + qo);
#pragma unroll
        for (int nt = 0; nt < 2; nt++)
          bf[nt] = *(const bf16x8*)(qb + (w * 32 + nt * 16 + x) * 128 + qo);
#pragma unroll
        for (int mt = 0; mt < 4; mt++)
#pragma unroll
          for (int nt = 0; nt < 2; nt++)
            eacc[mt][nt] = __builtin_amdgcn_mfma_f32_16x16x32_bf16(af[mt], bf[nt], eacc[mt][nt], 0, 0, 0);
      }
      raw_barrier();
    }
    // ---- E epilogue: exp2, z accumulate, swizzled bf16 write to E-LDS ----
#pragma unroll
    for (int mt = 0; mt < 4; mt++)
#pragma unroll
      for (int nt = 0; nt < 2; nt++)
#pragma unroll
        for (int r = 0; r < 4; r++) {
          float v = __builtin_amdgcn_exp2f(eacc[mt][nt][r] * scale);
          zr[mt][r] += v;
          const int row = mt * 16 + hi * 4 + r;
          const int col = w * 32 + nt * 16 + x;
          *(short*)(elds + ((row * 256 + col * 2) ^ ((row & 7) << 4))) = bf16_bits(v);
        }
    __syncthreads();
    // ---- PV: acc2 += E(bf16) * vb^T over this n-tile (k = 128 = 4 ksub) ----
    const long ng0 = (long)nc0 + t * 128;
#pragma unroll
    for (int ks = 0; ks < 4; ks++) {
      bf16x8 a[4], b[8];
#pragma unroll
      for (int mt = 0; mt < 4; mt++) {
        const int row = mt * 16 + x;
        a[mt] = *(const bf16x8*)(elds + ((row * 256 + ks * 64 + hi * 16) ^ ((row & 7) << 4)));
      }
#pragma unroll
      for (int ct = 0; ct < 8; ct++) {
        const int c = w * 128 + ct * 16 + x;
        b[ct] = *(const bf16x8*)(vg + ((size_t)c * 4096 + ng0 + ks * 32) * 2 + hi * 16);
      }
#pragma unroll
      for (int mt = 0; mt < 4; mt++)
#pragma unroll
        for (int ct = 0; ct < 8; ct++)
          acc2[mt][ct] = __builtin_amdgcn_mfma_f32_16x16x32_bf16(a[mt], b[ct], acc2[mt][ct], 0, 0, 0);
    }
    // next-tile staging: only after all C++ global loads consumed (vmcnt-safe)
    if (t < 7) { drain_vm(); stage(smem, t + 1, 0); }
  }

  // ---- block end: z reduce -> zsum; acc2 -> pvp (f32 partials) ----
#pragma unroll
  for (int mt = 0; mt < 4; mt++)
#pragma unroll
    for (int r = 0; r < 4; r++) {
      float z = zr[mt][r];
      z += __shfl_xor(z, 1); z += __shfl_xor(z, 2);
      z += __shfl_xor(z, 4); z += __shfl_xor(z, 8);
      zr[mt][r] = z;
    }
  if (x == 0) {
#pragma unroll
    for (int mt = 0; mt < 4; mt++)
#pragma unroll
      for (int r = 0; r < 4; r++)
        zbuf[w * 64 + mt * 16 + hi * 4 + r] = zr[mt][r];
  }
  __syncthreads();
  if (tid < 64) {
    float s = zbuf[tid] + zbuf[64 + tid] + zbuf[128 + tid] + zbuf[192 + tid];
    zsum_g[((size_t)bz * 4 + chunk) * 4096 + m0 + tid] = s;
  }
  float* pb = pvp + (((size_t)bz * 4 + chunk) * 4096 + m0) * 512;
#pragma unroll
  for (int mt = 0; mt < 4; mt++)
#pragma unroll
    for (int ct = 0; ct < 8; ct++)
#pragma unroll
      for (int r = 0; r < 4; r++) {
        const int row = mt * 16 + hi * 4 + r;
        const int c = w * 128 + ct * 16 + x;
        pb[(size_t)row * 512 + c] = acc2[mt][ct][r];
      }
}

// ---------------- Combine: ht2[b][n][c] = bf16( sum_p pvp / sum_p z ) ----------------
__global__ __launch_bounds__(256) void pv_combine(const float* __restrict__ pvp,
                                                  const float* __restrict__ zsum,
                                                  __hip_bfloat16* __restrict__ ht2) {
  int idx = blockIdx.x * 256 + threadIdx.x;    // 524288 units of 8 c
  int b = idx >> 18, r = idx & 262143;
  int n = r >> 6, c8 = (r & 63) * 8;
  const float* zp = zsum + (size_t)b * 4 * 4096 + n;
  float zv = zp[0] + zp[4096] + zp[2 * 4096] + zp[3 * 4096];
  float inv = 1.0f / zv;
  const float* pp = pvp + ((size_t)b * 4 * 4096 + n) * 512 + c8;
  float4 s0 = *(const float4*)(pp);
  float4 s1 = *(const float4*)(pp + 4);
#pragma unroll
  for (int p = 1; p < 4; p++) {
    const float* q = pp + (size_t)p * 4096 * 512;
    float4 a = *(const float4*)(q);
    float4 c = *(const float4*)(q + 4);
    s0.x += a.x; s0.y += a.y; s0.z += a.z; s0.w += a.w;
    s1.x += c.x; s1.y += c.y; s1.z += c.z; s1.w += c.w;
  }
  union { short s[8]; int4 v; } u;
  u.s[0] = bf16_bits(s0.x * inv); u.s[1] = bf16_bits(s0.y * inv);
  u.s[2] = bf16_bits(s0.z * inv); u.s[3] = bf16_bits(s0.w * inv);
  u.s[4] = bf16_bits(s1.x * inv); u.s[5] = bf16_bits(s1.y * inv);
  u.s[6] = bf16_bits(s1.z * inv); u.s[7] = bf16_bits(s1.w * inv);
  *(int4*)(ht2 + ((size_t)b * 4096 + n) * 512 + c8) = u.v;
}

extern "C" void kernel_launch(void* const* d_in, const int* in_sizes, int n_in,
                              void* d_out, int out_size, void* d_ws, size_t ws_size,
                              hipStream_t stream) {
  const float* x      = (const float*)d_in[0];
  const float* norm_w = (const float*)d_in[1];
  const float* norm_b = (const float*)d_in[2];
  const float* wq = (const float*)d_in[3];
  const float* bq = (const float*)d_in[4];
  const float* wk = (const float*)d_in[5];
  const float* bk = (const float*)d_in[6];
  const float* wv = (const float*)d_in[7];
  const float* bv = (const float*)d_in[8];
  const float* wp = (const float*)d_in[9];
  const float* bp = (const float*)d_in[10];
  float* out = (float*)d_out;

  const long CN = (long)CDIM * NDIM;       // 2M elems
  const long QKN = (long)NDIM * 1024;      // merged q|k, [N,1024]
  char* p = (char*)d_ws;
  auto carve = [&](size_t bytes) { char* r = p; p += (bytes + 255) & ~(size_t)255; return r; };
  __hip_bfloat16* h_t  = (__hip_bfloat16*)carve(BATCH * CN * 2);   // [B,N,C]
  __hip_bfloat16* wb   = (__hip_bfloat16*)carve(4 * 512 * 512 * 2);
  __hip_bfloat16* qk_t = (__hip_bfloat16*)carve(BATCH * QKN * 2);  // [B,N,1024]: q 0-511, k 512-1023
  __hip_bfloat16* vb   = (__hip_bfloat16*)carve(BATCH * CN * 2);   // [B,C,N]
  __hip_bfloat16* ht2  = (__hip_bfloat16*)carve(BATCH * CN * 2);   // [B,N,C]
  float* pvp   = (float*)carve((size_t)BATCH * 4 * NDIM * 512 * 4);  // 64 MB f32 partials
  float* zsum  = (float*)carve((size_t)BATCH * 4 * NDIM * 4);
  float* bqk   = (float*)carve(1024 * 4);
  float2* stats = (float2*)carve(BATCH * NGROUPS * sizeof(float2));
  float2* gnpart = (float2*)carve(1024 * sizeof(float2));
  __hip_bfloat16* wbv = wb + 524288;
  __hip_bfloat16* wbp = wb + 786432;

  const float scale_l2e = 0.06375872681318217f;  // 512^-0.5 * log2(e) for exp2-based softmax

  gn_stats_p1<<<dim3(1024), 256, 0, stream>>>(x, gnpart);
  gn_stats_p2<<<dim3(1), 64, 0, stream>>>(gnpart, stats);
  gn_apply_t<<<dim3(NDIM / 64, CDIM / 64, BATCH), 256, 0, stream>>>(x, stats, norm_w, norm_b, h_t);
  cvt_w<<<dim3(1024), 256, 0, stream>>>(wq, wk, wv, wp, wb, bq, bk, bqk);

  // qk_t[n][0..1023] = h_t @ [wq;wk]^T + [bq;bk]   (SWIZ; BK=64; 3/CU)
  mfma_gemm_nt<128, 64, 2, 2, false, 1, false, false, true, 3, 2><<<dim3(16, 32, BATCH), 256, 0, stream>>>(
      h_t, wb, bqk, nullptr, qk_t, nullptr, nullptr,
      NDIM, 1024, CDIM, CN, 0, QKN, CDIM, CDIM, 1024, 1.0f);
  // v = wv @ h_t^T + bv -> [C, N]   (BK=64; 3/CU)
  mfma_gemm_nt<64, 128, 2, 1, false, 1, false, false, false, 3, 2><<<dim3(32, 8, BATCH), 256, 0, stream>>>(
      wbv, h_t, bv, nullptr, vb, nullptr, nullptr,
      CDIM, NDIM, CDIM, 0, CN, CN, CDIM, CDIM, NDIM, 1.0f);
  // Fused S+PV: no St materialization; 4 f32 partial chunks + z partials
  fused_spv<<<dim3(512), 256, 0, stream>>>(qk_t, vb, pvp, zsum, scale_l2e);
  // ht2 = (sum_p pvp) / (sum_p z) -> [B,N,C] bf16
  pv_combine<<<dim3(2048), 256, 0, stream>>>(pvp, zsum, ht2);
  // out = wp @ ht2^T + bp + x -> [C, N] fp32 (residual fused in store phase; 3/CU)
  mfma_gemm_nt<64, 128, 2, 1, true, 0, false, false, false, 3, 2><<<dim3(32, 8, BATCH), 256, 0, stream>>>(
      wbp, ht2, bp, x, out, nullptr, nullptr,
      CDIM, NDIM, CDIM, 0, CN, CN, CDIM, CDIM, NDIM, 1.0f);
}

// Round 7
// 228.532 us; speedup vs baseline: 2.0404x; 2.0404x over previous
//
#include <hip/hip_runtime.h>
#include <hip/hip_bf16.h>

// B=2, C=512, H=W=64 -> N=4096, 32 groups of 16 channels
#define BATCH 2
#define CDIM 512
#define NDIM 4096
#define NGROUPS 32
#define CHPG 16
#define GN_EPS 1e-6f

typedef __attribute__((ext_vector_type(8))) short bf16x8;   // 8 bf16 = 4 VGPRs
typedef __attribute__((ext_vector_type(4))) float f32x4;

__device__ __forceinline__ void gl_lds16(const void* g, void* lds) {
  __builtin_amdgcn_global_load_lds((__attribute__((address_space(1))) void*)(g),
                                   (__attribute__((address_space(3))) void*)(lds), 16, 0, 0);
}

template <int N>
__device__ __forceinline__ void wait_vmcnt() {
  if constexpr (N == 1) asm volatile("s_waitcnt vmcnt(1)" ::: "memory");
  else if constexpr (N == 2) asm volatile("s_waitcnt vmcnt(2)" ::: "memory");
  else if constexpr (N == 3) asm volatile("s_waitcnt vmcnt(3)" ::: "memory");
  else if constexpr (N == 4) asm volatile("s_waitcnt vmcnt(4)" ::: "memory");
  else if constexpr (N == 5) asm volatile("s_waitcnt vmcnt(5)" ::: "memory");
  else if constexpr (N == 6) asm volatile("s_waitcnt vmcnt(6)" ::: "memory");
  else if constexpr (N == 8) asm volatile("s_waitcnt vmcnt(8)" ::: "memory");
  else if constexpr (N == 12) asm volatile("s_waitcnt vmcnt(12)" ::: "memory");
  else asm volatile("s_waitcnt vmcnt(8)" ::: "memory");
}

__device__ __forceinline__ void raw_barrier() {
  asm volatile("s_barrier" ::: "memory");
}

__device__ __forceinline__ void drain_vm() {
  asm volatile("s_waitcnt vmcnt(0)" ::: "memory");
}

__device__ __forceinline__ short bf16_bits(float v) {
  __hip_bfloat16 h = __float2bfloat16(v);
  union { __hip_bfloat16 h; short s; } u;
  u.h = h;
  return u.s;
}

// ---------------- GroupNorm stats, two-stage ----------------
__global__ __launch_bounds__(256) void gn_stats_p1(const float* __restrict__ x,
                                                   float2* __restrict__ part) {
  int blk = blockIdx.x;
  int chunk = blk & 15, bg = blk >> 4;
  const float4* p = (const float4*)(x + (size_t)bg * (CHPG * NDIM) + chunk * 4096);
  float s = 0.f, ss = 0.f;
#pragma unroll
  for (int t = 0; t < 4; t++) {
    float4 v = p[threadIdx.x + t * 256];
    s += v.x + v.y + v.z + v.w;
    ss += v.x * v.x + v.y * v.y + v.z * v.z + v.w * v.w;
  }
  int w = threadIdx.x >> 6, l = threadIdx.x & 63;
#pragma unroll
  for (int off = 32; off > 0; off >>= 1) {
    s += __shfl_down(s, off);
    ss += __shfl_down(ss, off);
  }
  __shared__ float r1[4], r2[4];
  if (l == 0) { r1[w] = s; r2[w] = ss; }
  __syncthreads();
  if (threadIdx.x == 0)
    part[blk] = make_float2(r1[0] + r1[1] + r1[2] + r1[3], r2[0] + r2[1] + r2[2] + r2[3]);
}

__global__ __launch_bounds__(64) void gn_stats_p2(const float2* __restrict__ part,
                                                  float2* __restrict__ stats) {
  int bg = threadIdx.x;  // 64
  float s = 0.f, ss = 0.f;
#pragma unroll
  for (int c = 0; c < 16; c++) {
    float2 v = part[bg * 16 + c];
    s += v.x; ss += v.y;
  }
  const float inv = 1.0f / (CHPG * NDIM);
  float mean = s * inv;
  float var = ss * inv - mean * mean;
  stats[bg] = make_float2(mean, rsqrtf(var + GN_EPS));
}

// ------ GroupNorm apply + transpose to channel-last bf16: h_t[b][n][c] ------
__global__ __launch_bounds__(256) void gn_apply_t(const float* __restrict__ x,
                                                  const float2* __restrict__ stats,
                                                  const float* __restrict__ w,
                                                  const float* __restrict__ bias,
                                                  __hip_bfloat16* __restrict__ ht) {
  __shared__ __hip_bfloat16 tile[64][66];
  int b = blockIdx.z, c0 = blockIdx.y * 64, n0 = blockIdx.x * 64;
  int tq = threadIdx.x >> 6;
  int tl = threadIdx.x & 63;
#pragma unroll
  for (int i = 0; i < 16; i++) {
    int cl = tq * 16 + i;
    int c = c0 + cl;
    float2 st = stats[b * NGROUPS + (c >> 4)];
    float v = x[((size_t)b * CDIM + c) * NDIM + n0 + tl];
    v = (v - st.x) * st.y * w[c] + bias[c];
    tile[tl][cl] = __float2bfloat16(v);
  }
  __syncthreads();
#pragma unroll
  for (int i = 0; i < 16; i++) {
    int nl = tq * 16 + i;
    ht[((size_t)b * NDIM + n0 + nl) * CDIM + c0 + tl] = tile[nl][tl];
  }
}

// --- fp32 -> bf16 weights; also concat [bq;bk] bias into bqk (block 0) ---
__global__ __launch_bounds__(256) void cvt_w(const float* __restrict__ a, const float* __restrict__ b,
                                             const float* __restrict__ c, const float* __restrict__ d,
                                             __hip_bfloat16* __restrict__ o,
                                             const float* __restrict__ bq, const float* __restrict__ bk,
                                             float* __restrict__ bqk) {
  int i = blockIdx.x * 256 + threadIdx.x;
  o[i]          = __float2bfloat16(a[i]);
  o[i + 262144] = __float2bfloat16(b[i]);
  o[i + 524288] = __float2bfloat16(c[i]);
  o[i + 786432] = __float2bfloat16(d[i]);
  if (blockIdx.x == 0) {
#pragma unroll
    for (int t = 0; t < 4; t++) {
      int j = threadIdx.x + t * 256;  // 0..1023
      bqk[j] = (j < 512) ? bq[j] : bk[j - 512];
    }
  }
}

// ---------------- MFMA NT GEMM, pipelined + LDS-swizzled ----------------
// C[m][n] = scale * sum_k A[m][k]*B[n][k]  (+bias) (+res)
// A: [M x K] bf16 row stride lda; B: [N x K] bf16 row stride ldb; C stride ldc.
// BK = 32*KU, 4 waves (2x2), wave tile (MT/2)x(NT/2).
// K-loop: NBUF-deep LDS ring (NBUF=2: 1-ahead prefetch, wait vmcnt(NL);
// NBUF=3: 2-ahead prefetch, wait vmcnt(2*NL)), raw barriers; staging column
// swizzle keeps fragment ds_read_b128 conflict-free for KU=2 (8 slots);
// KU=1's 4-slot pattern has inherent 2-way aliasing (measured ~free).
// Epilogue: LDS repack -> coalesced 16B stores.
// EXPZ: value=exp2(value) -- caller pre-folds log2(e) into scale; per-
//       (half-tile) row sums -> zsum_g[b][bx*2+wx][m] (64 partials, grid.x=32).
// SCALEM: value *= cinv_g[b][m].
// OUT_MODE: 0 f32, 1 bf16. BIAS_MODE: 0 none, 1 bias[m], 2 bias[n].
// SWIZ (grid (GX,32,z)): co-locate A-sharing blocks on one XCD (bijective
// when GX*32 % 8 == 0, true for all uses here).
template <int MT, int NT, int KU, int BIAS_MODE, bool HAS_RES, int OUT_MODE,
          bool EXPZ, bool SCALEM, bool SWIZ, int MINB, int NBUF>
__global__ __launch_bounds__(256, MINB) void mfma_gemm_nt(
    const __hip_bfloat16* __restrict__ A, const __hip_bfloat16* __restrict__ B,
    const float* __restrict__ bias, const float* __restrict__ res,
    void* __restrict__ Cout, float* __restrict__ zsum_g, const float* __restrict__ cinv_g,
    int M, int N, int K, long sA, long sB, long sC,
    long lda, long ldb, long ldc, float scale) {
  constexpr int MTI = MT / 32, NTI = NT / 32;   // 16x16 acc tiles per wave
  constexpr int SB = 64 * KU;                   // bytes per row k-slab
  constexpr int ABYT = MT * SB, BBYT = NT * SB;
  constexpr int BUFB = ABYT + BBYT;
  constexpr int AISS = MT * KU / 64, BISS = NT * KU / 64;
  constexpr int NL = AISS + BISS;
  constexpr int RPI = 16 / KU;                  // rows per staging issue
  constexpr int ES = (OUT_MODE == 0) ? 4 : 2;   // out element size
  constexpr int RS = NT * ES + 16;              // repack row stride (pad = 16B)
  constexpr int REPB = MT * RS;
  constexpr int SMEMB = (NBUF * BUFB > REPB) ? NBUF * BUFB : REPB;
  constexpr int CPR = NT * ES / 16;             // 16B chunks per row
  constexpr int NCH = MT * CPR / 256;           // chunks per thread
  __shared__ char smem[SMEMB];
  const int tid = threadIdx.x;
  const int w = tid >> 6, l = tid & 63;
  const int wy = w >> 1, wx = w & 1;
  const int bz = blockIdx.z;
  int bx = blockIdx.x, by = blockIdx.y;
  if constexpr (SWIZ) {
    int l2 = by * gridDim.x + bx;
    int xcd = l2 & 7, s = l2 >> 3;
    by = xcd + (s & 3) * 8;
    bx = s >> 2;
  }
  const int m0 = by * MT, n0 = bx * NT;
  f32x4 acc[MTI][NTI] = {};

  // staging source column swizzle (bytes within the SB row-slab)
  int so;
  if constexpr (KU == 1) so = (((l & 3) - (l >> 2) - (l >> 4)) & 3) * 16;
  else                   so = (((l & 7) - (l >> 3)) & 7) * 16;
  const int lrow = (KU == 1) ? (l >> 2) : (l >> 3);
  const int arow = w * (MT / 4) + lrow;
  const int brow = w * (NT / 4) + lrow;
  const char* Ag = (const char*)A + ((size_t)bz * sA + (size_t)(m0 + arow) * lda) * 2 + so;
  const char* Bg = (const char*)B + ((size_t)bz * sB + (size_t)(n0 + brow) * ldb) * 2 + so;
  const size_t iadvA = (size_t)RPI * lda * 2;
  const size_t iadvB = (size_t)RPI * ldb * 2;
  const int woffA = w * (MT / 4) * SB;
  const int woffB = ABYT + w * (NT / 4) * SB;

  auto issue = [&](int buf) {
    char* base = smem + buf * BUFB;
#pragma unroll
    for (int i = 0; i < AISS; i++) gl_lds16(Ag + i * iadvA, base + woffA + i * 1024);
#pragma unroll
    for (int i = 0; i < BISS; i++) gl_lds16(Bg + i * iadvB, base + woffB + i * 1024);
    Ag += SB; Bg += SB;
  };

  // fragment-read column offsets (per KU half)
  const int x = l & 15;
  int qr0, qr1 = 0;
  if constexpr (KU == 1) {
    qr0 = (((l >> 4) + x + (x >> 2)) & 3) * 16;
  } else {
    qr0 = (((l >> 4) + (l & 7)) & 7) * 16;
    qr1 = (((l >> 4) + 4 + (l & 7)) & 7) * 16;
  }

  issue(0);
  if constexpr (NBUF == 3) issue(1);
  const int T = K / (32 * KU);
  for (int t = 0; t < T; t++) {
    issue((t + NBUF - 1) % NBUF);   // prefetch t+NBUF-1 (tail overshoots <=(NBUF-1)*SB, lands in ws)
    wait_vmcnt<(NBUF - 1) * NL>();  // oldest in-flight slab (t) landed
    raw_barrier();
    const char* Asb = smem + (t % NBUF) * BUFB;
    const char* Bsb = Asb + ABYT;
#pragma unroll
    for (int h = 0; h < KU; h++) {
      const int q = (h == 0) ? qr0 : qr1;
      bf16x8 af[MTI], bfr[NTI];
#pragma unroll
      for (int mt = 0; mt < MTI; mt++)
        af[mt] = *(const bf16x8*)(Asb + (wy * (MT / 2) + mt * 16 + x) * SB + q);
#pragma unroll
      for (int nt = 0; nt < NTI; nt++)
        bfr[nt] = *(const bf16x8*)(Bsb + (wx * (NT / 2) + nt * 16 + x) * SB + q);
#pragma unroll
      for (int mt = 0; mt < MTI; mt++)
#pragma unroll
        for (int nt = 0; nt < NTI; nt++)
          acc[mt][nt] = __builtin_amdgcn_mfma_f32_16x16x32_bf16(af[mt], bfr[nt], acc[mt][nt], 0, 0, 0);
    }
    raw_barrier();            // all waves done reading buf before it is overwritten
  }

  // ---- epilogue: value phase -> LDS repack -> coalesced store phase ----
  drain_vm();      // stray tail prefetches landed
  raw_barrier();
  const size_t cbase = (size_t)bz * sC;
#pragma unroll
  for (int mt = 0; mt < MTI; mt++) {
#pragma unroll
    for (int r = 0; r < 4; r++) {
      const int row = wy * (MT / 2) + mt * 16 + (l >> 4) * 4 + r;  // block-local m
      float bvm = (BIAS_MODE == 1) ? bias[m0 + row] : 0.f;
      float cm = 1.f;
      if constexpr (SCALEM) cm = cinv_g[(size_t)bz * M + m0 + row];
      float z = 0.f;
#pragma unroll
      for (int nt = 0; nt < NTI; nt++) {
        const int nl = wx * (NT / 2) + nt * 16 + x;
        float v = acc[mt][nt][r] * scale + bvm;
        if (BIAS_MODE == 2) v += bias[n0 + nl];
        if constexpr (EXPZ) { v = __builtin_amdgcn_exp2f(v); z += v; }
        if constexpr (SCALEM) v *= cm;
        if (OUT_MODE == 0) *(float*)(smem + row * RS + nl * 4) = v;
        else *(short*)(smem + row * RS + nl * 2) = bf16_bits(v);
      }
      if constexpr (EXPZ) {
        z += __shfl_xor(z, 1); z += __shfl_xor(z, 2);
        z += __shfl_xor(z, 4); z += __shfl_xor(z, 8);
        if (x == 0)
          zsum_g[((size_t)bz * 64 + bx * 2 + wx) * M + m0 + row] = z;
      }
    }
  }
  __syncthreads();
#pragma unroll
  for (int i = 0; i < NCH; i++) {
    const int g = i * 256 + tid;
    const int row = g / CPR;
    const int off = (g % CPR) * 16;
    char* dst = (char*)Cout + (cbase + (size_t)(m0 + row) * ldc + n0) * ES + off;
    if (OUT_MODE == 0) {
      float4 d = *(float4*)(smem + row * RS + off);
      if constexpr (HAS_RES) {
        float4 rv = *(const float4*)((const char*)res + (cbase + (size_t)(m0 + row) * ldc + n0) * 4 + off);
        d.x += rv.x; d.y += rv.y; d.z += rv.z; d.w += rv.w;
      }
      *(float4*)dst = d;
    } else {
      int4 d = *(int4*)(smem + row * RS + off);
      *(int4*)dst = d;
    }
  }
}

// ---------------- Z combine: cinv[b][j] = 1 / sum_p zsum[b][p][j] ----------------
__global__ __launch_bounds__(256) void zcomb(const float* __restrict__ zsum,
                                             float* __restrict__ cinv) {
  int idx = blockIdx.x * 256 + threadIdx.x;  // b*NDIM + j, 8192 total
  int b = idx >> 12, j = idx & (NDIM - 1);
  float s = 0.f;
#pragma unroll 8
  for (int p = 0; p < 64; p++) s += zsum[((size_t)b * 64 + p) * NDIM + j];
  cinv[idx] = 1.0f / s;
}

extern "C" void kernel_launch(void* const* d_in, const int* in_sizes, int n_in,
                              void* d_out, int out_size, void* d_ws, size_t ws_size,
                              hipStream_t stream) {
  const float* x      = (const float*)d_in[0];
  const float* norm_w = (const float*)d_in[1];
  const float* norm_b = (const float*)d_in[2];
  const float* wq = (const float*)d_in[3];
  const float* bq = (const float*)d_in[4];
  const float* wk = (const float*)d_in[5];
  const float* bk = (const float*)d_in[6];
  const float* wv = (const float*)d_in[7];
  const float* bv = (const float*)d_in[8];
  const float* wp = (const float*)d_in[9];
  const float* bp = (const float*)d_in[10];
  float* out = (float*)d_out;

  const long CN = (long)CDIM * NDIM;       // 2M elems
  const long NN = (long)NDIM * NDIM;       // 16M elems
  const long QKN = (long)NDIM * 1024;      // merged q|k, [N,1024]
  char* p = (char*)d_ws;
  auto carve = [&](size_t bytes) { char* r = p; p += (bytes + 255) & ~(size_t)255; return r; };
  __hip_bfloat16* h_t  = (__hip_bfloat16*)carve(BATCH * CN * 2);   // [B,N,C]
  __hip_bfloat16* wb   = (__hip_bfloat16*)carve(4 * 512 * 512 * 2);
  __hip_bfloat16* qk_t = (__hip_bfloat16*)carve(BATCH * QKN * 2);  // [B,N,1024]: q 0-511, k 512-1023
  __hip_bfloat16* vb   = (__hip_bfloat16*)carve(BATCH * CN * 2);   // [B,C,N]
  __hip_bfloat16* ht2  = (__hip_bfloat16*)carve(BATCH * CN * 2);   // [B,N,C]
  __hip_bfloat16* St   = (__hip_bfloat16*)carve(BATCH * NN * 2);   // [B,N,N] E^T = exp(S^T)
  float* zsum  = (float*)carve((size_t)BATCH * 64 * NDIM * 4);     // slack for stray prefetch
  float* cinv  = (float*)carve(BATCH * NDIM * 4);
  float* bqk   = (float*)carve(1024 * 4);
  float2* stats = (float2*)carve(BATCH * NGROUPS * sizeof(float2));
  float2* gnpart = (float2*)carve(1024 * sizeof(float2));
  __hip_bfloat16* wbv = wb + 524288;
  __hip_bfloat16* wbp = wb + 786432;

  const float scale_l2e = 0.06375872681318217f;  // 512^-0.5 * log2(e), for exp2-based EXPZ

  gn_stats_p1<<<dim3(1024), 256, 0, stream>>>(x, gnpart);
  gn_stats_p2<<<dim3(1), 64, 0, stream>>>(gnpart, stats);
  gn_apply_t<<<dim3(NDIM / 64, CDIM / 64, BATCH), 256, 0, stream>>>(x, stats, norm_w, norm_b, h_t);
  cvt_w<<<dim3(1024), 256, 0, stream>>>(wq, wk, wv, wp, wb, bq, bk, bqk);

  // qk_t[n][0..1023] = h_t @ [wq;wk]^T + [bq;bk]   (SWIZ; BK=64; 3/CU)
  mfma_gemm_nt<128, 64, 2, 2, false, 1, false, false, true, 3, 2><<<dim3(16, 32, BATCH), 256, 0, stream>>>(
      h_t, wb, bqk, nullptr, qk_t, nullptr, nullptr,
      NDIM, 1024, CDIM, CN, 0, QKN, CDIM, CDIM, 1024, 1.0f);
  // v = wv @ h_t^T + bv -> [C, N]   (BK=64; 3/CU)
  mfma_gemm_nt<64, 128, 2, 1, false, 1, false, false, false, 3, 2><<<dim3(32, 8, BATCH), 256, 0, stream>>>(
      wbv, h_t, bv, nullptr, vb, nullptr, nullptr,
      CDIM, NDIM, CDIM, 0, CN, CN, CDIM, CDIM, NDIM, 1.0f);
  // E^T = exp2(k_t @ q_t^T * scale_l2e) -> [N, N] bf16, fused partial Z row-sums
  // Best-measured S config (R1: 61.6us): 128x128, BK=32, 3-buf ring
  // (2-deep prefetch, vmcnt(8)), 3 blocks/CU. NEW: SWIZ=true (T1) -- blocks
  // sharing k-rows (same by) co-located per XCD for L2 reuse of qk_t.
  mfma_gemm_nt<128, 128, 1, 0, false, 1, true, false, true, 3, 3><<<dim3(32, 32, BATCH), 256, 0, stream>>>(
      qk_t + 512, qk_t, nullptr, nullptr, St, zsum, nullptr,
      NDIM, NDIM, CDIM, QKN, QKN, NN, 1024, 1024, NDIM, scale_l2e);
  zcomb<<<dim3(32), 256, 0, stream>>>(zsum, cinv);
  // ht2 = diag(cinv) (E^T @ v^T) -> [N, C]   (SWIZ; BK=64; NBUF=3, 2/CU --
  // measured clean in R4)
  mfma_gemm_nt<128, 64, 2, 0, false, 1, false, true, true, 2, 3><<<dim3(8, 32, BATCH), 256, 0, stream>>>(
      St, vb, nullptr, nullptr, ht2, nullptr, cinv,
      NDIM, CDIM, NDIM, NN, CN, CN, NDIM, NDIM, CDIM, 1.0f);
  // out = wp @ ht2^T + bp + x -> [C, N] fp32 (residual fused in store phase; 3/CU)
  mfma_gemm_nt<64, 128, 2, 1, true, 0, false, false, false, 3, 2><<<dim3(32, 8, BATCH), 256, 0, stream>>>(
      wbp, ht2, bp, x, out, nullptr, nullptr,
      CDIM, NDIM, CDIM, 0, CN, CN, CDIM, CDIM, NDIM, 1.0f);
}